// Round 1
// baseline (84.285 us; speedup 1.0000x reference)
//
#include <hip/hip_runtime.h>

#define BB 4
#define CC 256
#define HH 50
#define WW 50
#define KK 1000
#define PP 7              // pooled H == pooled W
#define NBIN (PP * PP)    // 49
#define SCALE 0.0625f     // 1/16

// --- per-axis sample computation, replicating reference boundary handling ---
// For pooled index p (SR=2 samples), produce 4 (index, weight) taps.
__device__ __forceinline__ void axis_samples(float start, float bin, int p, float limit,
                                             int idx[4], float w[4]) {
#pragma unroll
    for (int i = 0; i < 2; ++i) {
        float s = (float)(p * 2 + i);
        // c = start + bin_size*(s+0.5)/SR ; /2 is exact as *0.5
        float c = start + bin * (s + 0.5f) * 0.5f;
        bool valid = (c > -1.0f) && (c < limit);
        c = fmaxf(c, 0.0f);
        float low = floorf(c);
        float high;
        if (low >= limit - 1.0f) { low = limit - 1.0f; c = low; high = low; }
        else high = low + 1.0f;
        float frac = c - low;
        idx[i * 2 + 0] = (int)low;
        idx[i * 2 + 1] = (int)high;
        w[i * 2 + 0] = valid ? (1.0f - frac) : 0.0f;
        w[i * 2 + 1] = valid ? frac : 0.0f;
    }
}

// --- NCHW -> NHWC transpose (one block per (b, y) row) ---
__global__ __launch_bounds__(256) void xpose_kernel(const float* __restrict__ in,
                                                    float* __restrict__ out) {
    __shared__ float tile[CC * WW];           // 51200 B
    const int b = blockIdx.x / HH;
    const int y = blockIdx.x % HH;
    const int t = threadIdx.x;
    for (int i = t; i < CC * WW; i += 256) {  // i = c*WW + x : coalesced-ish read
        tile[i] = in[((size_t)(b * CC + (i / WW)) * HH + y) * WW + (i % WW)];
    }
    __syncthreads();
    for (int i = t; i < CC * WW; i += 256) {  // i = x*CC + c : coalesced write
        int x = i / CC, c = i % CC;
        out[((size_t)(b * HH + y) * WW + x) * CC + c] = tile[c * WW + x];
    }
}

// --- main ROI-align gather: one block per ROI, thread = channel ---
template <bool NHWC>
__global__ __launch_bounds__(256) void roialign_kernel(const float* __restrict__ fmap,
                                                       const float* __restrict__ rois,
                                                       float* __restrict__ out) {
    __shared__ float sbuf[CC * NBIN];         // 50176 B, laid out [c][49]
    const int k = blockIdx.x;
    const int t = threadIdx.x;                // channel

    const float bf = rois[k * 5 + 0];
    const int b = (int)bf;
    const float x1 = rois[k * 5 + 1] * SCALE;
    const float y1 = rois[k * 5 + 2] * SCALE;
    const float x2 = rois[k * 5 + 3] * SCALE;
    const float y2 = rois[k * 5 + 4] * SCALE;
    const float roi_w = fmaxf(x2 - x1, 1.0f);
    const float roi_h = fmaxf(y2 - y1, 1.0f);
    const float bw = roi_w / (float)PP;
    const float bh = roi_h / (float)PP;

    for (int ph = 0; ph < PP; ++ph) {
        int ys[4]; float wy[4];
        axis_samples(y1, bh, ph, (float)HH, ys, wy);
        for (int pw = 0; pw < PP; ++pw) {
            int xs[4]; float wx[4];
            axis_samples(x1, bw, pw, (float)WW, xs, wx);
            float acc = 0.0f;
#pragma unroll
            for (int i = 0; i < 4; ++i) {
#pragma unroll
                for (int j = 0; j < 4; ++j) {
                    float wgt = wy[i] * wx[j];
                    float v;
                    if (NHWC) {
                        v = fmap[((size_t)(b * HH + ys[i]) * WW + xs[j]) * CC + t];
                    } else {
                        v = fmap[((size_t)(b * CC + t) * HH + ys[i]) * WW + xs[j]];
                    }
                    acc = fmaf(wgt, v, acc);
                }
            }
            sbuf[t * NBIN + ph * PP + pw] = acc * 0.25f;  // stride 49 (odd) -> no bank conflict
        }
    }
    __syncthreads();
    // coalesced stream-out: 12544 contiguous floats per ROI
    float* o = out + (size_t)k * (CC * NBIN);
    const float4* s4 = (const float4*)sbuf;
    float4* o4 = (float4*)o;
    for (int i = t; i < (CC * NBIN) / 4; i += 256) {
        o4[i] = s4[i];
    }
}

extern "C" void kernel_launch(void* const* d_in, const int* in_sizes, int n_in,
                              void* d_out, int out_size, void* d_ws, size_t ws_size,
                              hipStream_t stream) {
    const float* input = (const float*)d_in[0];   // [B,C,H,W] f32
    const float* rois  = (const float*)d_in[1];   // [K,5] f32
    float* out = (float*)d_out;                   // [K,C,7,7] f32

    const size_t need = (size_t)BB * HH * WW * CC * sizeof(float);  // 10.24 MB
    if (ws_size >= need) {
        float* fmap = (float*)d_ws;
        xpose_kernel<<<BB * HH, 256, 0, stream>>>(input, fmap);
        roialign_kernel<true><<<KK, 256, 0, stream>>>(fmap, rois, out);
    } else {
        roialign_kernel<false><<<KK, 256, 0, stream>>>(input, rois, out);
    }
}

// Round 2
// 49.429 us; speedup vs baseline: 1.7052x; 1.7052x over previous
//
#include <hip/hip_runtime.h>

#define BB 4
#define CC 256
#define HH 50
#define WW 50
#define KK 1000
#define PP 7              // pooled H == pooled W
#define NBIN (PP * PP)    // 49
#define SCALE 0.0625f     // 1/16

// --- per-axis sample computation, replicating reference boundary handling ---
__device__ __forceinline__ void axis_samples(float start, float bin, int p, float limit,
                                             int idx[4], float w[4]) {
#pragma unroll
    for (int i = 0; i < 2; ++i) {
        float s = (float)(p * 2 + i);
        float c = start + bin * (s + 0.5f) * 0.5f;   // /SR==2 exact as *0.5
        bool valid = (c > -1.0f) && (c < limit);
        c = fmaxf(c, 0.0f);
        float low = floorf(c);
        float high;
        if (low >= limit - 1.0f) { low = limit - 1.0f; c = low; high = low; }
        else high = low + 1.0f;
        float frac = c - low;
        idx[i * 2 + 0] = (int)low;
        idx[i * 2 + 1] = (int)high;
        w[i * 2 + 0] = valid ? (1.0f - frac) : 0.0f;
        w[i * 2 + 1] = valid ? frac : 0.0f;
    }
}

// --- NCHW -> NHWC transpose: block per (b,y), 1024 threads ---
__global__ __launch_bounds__(1024) void xpose_kernel(const float* __restrict__ in,
                                                     float* __restrict__ out) {
    __shared__ float tile[CC * 51];           // stride 51 pad: 52224 B
    const int b = blockIdx.x / HH;
    const int y = blockIdx.x % HH;
    const int t = threadIdx.x;
    // read: float2 across [c][x], contiguous runs of 25 float2 per channel row
    for (int i = t; i < CC * 25; i += 1024) {
        const int c = i / 25, x2 = i % 25;
        const float2 v = *(const float2*)(in + (((size_t)(b * CC + c) * HH + y) * WW + 2 * x2));
        tile[c * 51 + 2 * x2]     = v.x;
        tile[c * 51 + 2 * x2 + 1] = v.y;
    }
    __syncthreads();
    float* ob = out + ((size_t)(b * HH + y) * WW) * CC;
    // write: float4 along channels, fully coalesced
    for (int j = t; j < WW * (CC / 4); j += 1024) {
        const int x  = j >> 6;        // 64 channel-quads per x
        const int c0 = (j & 63) * 4;
        float4 v = { tile[(c0 + 0) * 51 + x], tile[(c0 + 1) * 51 + x],
                     tile[(c0 + 2) * 51 + x], tile[(c0 + 3) * 51 + x] };
        *(float4*)(ob + (size_t)x * CC + c0) = v;
    }
}

// --- main gather: block per ROI, wave = bin, lane = channel-quad ---
__global__ __launch_bounds__(256) void roialign_kernel(const float4* __restrict__ fmap4,
                                                       const float* __restrict__ rois,
                                                       float4* __restrict__ out4) {
    __shared__ __align__(16) float sbuf[CC * NBIN];   // 50176 B, [c][49]
    __shared__ int   s_yi[PP][4], s_xi[PP][4];
    __shared__ float s_yw[PP][4], s_xw[PP][4];

    const int k = blockIdx.x;
    const int t = threadIdx.x;
    const int wave = t >> 6;
    const int lane = t & 63;

    const float bf = rois[k * 5 + 0];
    const int b = (int)bf;
    const float x1 = rois[k * 5 + 1] * SCALE;
    const float y1 = rois[k * 5 + 2] * SCALE;
    const float x2 = rois[k * 5 + 3] * SCALE;
    const float y2 = rois[k * 5 + 4] * SCALE;
    const float bw = fmaxf(x2 - x1, 1.0f) / (float)PP;
    const float bh = fmaxf(y2 - y1, 1.0f) / (float)PP;

    if (t < PP) {                       // y-axis tables
        int idx[4]; float w[4];
        axis_samples(y1, bh, t, (float)HH, idx, w);
#pragma unroll
        for (int j = 0; j < 4; ++j) { s_yi[t][j] = idx[j]; s_yw[t][j] = w[j]; }
    } else if (t >= 64 && t < 64 + PP) { // x-axis tables (different wave, parallel)
        const int p = t - 64;
        int idx[4]; float w[4];
        axis_samples(x1, bw, p, (float)WW, idx, w);
#pragma unroll
        for (int j = 0; j < 4; ++j) { s_xi[p][j] = idx[j]; s_xw[p][j] = w[j]; }
    }
    __syncthreads();

    const int base4 = b * (HH * WW * (CC / 4));      // float4 units
    for (int bin = wave; bin < NBIN; bin += 4) {
        const int ph = bin / PP;
        const int pw = bin - ph * PP;
        int rb[4], xo[4]; float wy[4], wx[4];
#pragma unroll
        for (int j = 0; j < 4; ++j) {
            rb[j] = base4 + s_yi[ph][j] * (WW * CC / 4);
            wy[j] = s_yw[ph][j];
            xo[j] = s_xi[pw][j] * (CC / 4) + lane;
            wx[j] = s_xw[pw][j];
        }
        float4 acc = {0.f, 0.f, 0.f, 0.f};
#pragma unroll
        for (int iy = 0; iy < 4; ++iy) {
#pragma unroll
            for (int ix = 0; ix < 4; ++ix) {
                const float wgt = wy[iy] * wx[ix];
                const float4 v = fmap4[rb[iy] + xo[ix]];
                acc.x = fmaf(wgt, v.x, acc.x);
                acc.y = fmaf(wgt, v.y, acc.y);
                acc.z = fmaf(wgt, v.z, acc.z);
                acc.w = fmaf(wgt, v.w, acc.w);
            }
        }
        const int c0 = 4 * lane;
        sbuf[(c0 + 0) * NBIN + bin] = acc.x * 0.25f;
        sbuf[(c0 + 1) * NBIN + bin] = acc.y * 0.25f;
        sbuf[(c0 + 2) * NBIN + bin] = acc.z * 0.25f;
        sbuf[(c0 + 3) * NBIN + bin] = acc.w * 0.25f;
    }
    __syncthreads();

    float4* o4 = out4 + (size_t)k * (CC * NBIN / 4);
    const float4* s4 = (const float4*)sbuf;
    for (int i = t; i < CC * NBIN / 4; i += 256) o4[i] = s4[i];
}

// --- fallback: direct NCHW, thread = channel (only if ws too small) ---
__global__ __launch_bounds__(256) void roialign_nchw_kernel(const float* __restrict__ fmap,
                                                            const float* __restrict__ rois,
                                                            float* __restrict__ out) {
    __shared__ __align__(16) float sbuf[CC * NBIN];
    const int k = blockIdx.x;
    const int t = threadIdx.x;

    const float bf = rois[k * 5 + 0];
    const int b = (int)bf;
    const float x1 = rois[k * 5 + 1] * SCALE;
    const float y1 = rois[k * 5 + 2] * SCALE;
    const float x2 = rois[k * 5 + 3] * SCALE;
    const float y2 = rois[k * 5 + 4] * SCALE;
    const float bw = fmaxf(x2 - x1, 1.0f) / (float)PP;
    const float bh = fmaxf(y2 - y1, 1.0f) / (float)PP;

    for (int ph = 0; ph < PP; ++ph) {
        int ys[4]; float wy[4];
        axis_samples(y1, bh, ph, (float)HH, ys, wy);
        for (int pw = 0; pw < PP; ++pw) {
            int xs[4]; float wx[4];
            axis_samples(x1, bw, pw, (float)WW, xs, wx);
            float acc = 0.0f;
#pragma unroll
            for (int i = 0; i < 4; ++i)
#pragma unroll
                for (int j = 0; j < 4; ++j)
                    acc = fmaf(wy[i] * wx[j],
                               fmap[((size_t)(b * CC + t) * HH + ys[i]) * WW + xs[j]], acc);
            sbuf[t * NBIN + ph * PP + pw] = acc * 0.25f;
        }
    }
    __syncthreads();
    float4* o4 = (float4*)(out + (size_t)k * (CC * NBIN));
    const float4* s4 = (const float4*)sbuf;
    for (int i = t; i < (CC * NBIN) / 4; i += 256) o4[i] = s4[i];
}

extern "C" void kernel_launch(void* const* d_in, const int* in_sizes, int n_in,
                              void* d_out, int out_size, void* d_ws, size_t ws_size,
                              hipStream_t stream) {
    const float* input = (const float*)d_in[0];   // [B,C,H,W] f32
    const float* rois  = (const float*)d_in[1];   // [K,5] f32
    float* out = (float*)d_out;                   // [K,C,7,7] f32

    const size_t need = (size_t)BB * HH * WW * CC * sizeof(float);  // 10.24 MB
    if (ws_size >= need) {
        float* fmap = (float*)d_ws;
        xpose_kernel<<<BB * HH, 1024, 0, stream>>>(input, fmap);
        roialign_kernel<<<KK, 256, 0, stream>>>((const float4*)fmap, rois, (float4*)out);
    } else {
        roialign_nchw_kernel<<<KK, 256, 0, stream>>>(input, rois, out);
    }
}